// Round 17
// baseline (198.957 us; speedup 1.0000x reference)
//
#include <hip/hip_runtime.h>
#include <math.h>

#define VOCABN 50000
#define HIDN 512
#define NROWS 4096
#define MTILE 64
#define FPB 64
#define MAXNS 40
#define ASLOTS 4480   // padded grouped-slot space (>= 4096 + 3*127), multiple of 16

typedef __attribute__((ext_vector_type(8))) short bf16x8;
typedef __attribute__((ext_vector_type(4))) float f32x4;
typedef __attribute__((ext_vector_type(4))) unsigned u32x4;
typedef __attribute__((ext_vector_type(4))) int i32x4;

#define XQS 15.875f          // 127/8  (x scale)
#define WQS 3175.0f          // 127/0.04 (w scale)
#define DEQ ((8.0f / 127.0f) * (0.04f / 127.0f))
#define L2E 1.44269504f
#define LN2 0.69314718f

// pack two fp32 into 2 bf16 (truncate): low16 = bf16(lo), high16 = bf16(hi)
__device__ __forceinline__ unsigned pk2(float hi, float lo) {
  return __builtin_amdgcn_perm(__builtin_bit_cast(unsigned, hi),
                               __builtin_bit_cast(unsigned, lo),
                               0x07060302u);
}

__device__ __forceinline__ void gload_lds16(const void* g, void* l) {
  __builtin_amdgcn_global_load_lds(
      (const __attribute__((address_space(1))) void*)g,
      (__attribute__((address_space(3))) void*)l, 16, 0, 0);
}

__device__ __forceinline__ unsigned q4(float a, float b, float c, float d, float s) {
  int q0 = max(-127, min(127, __float2int_rn(a * s)));
  int q1 = max(-127, min(127, __float2int_rn(b * s)));
  int q2 = max(-127, min(127, __float2int_rn(c * s)));
  int q3 = max(-127, min(127, __float2int_rn(d * s)));
  return (unsigned)(q0 & 255) | ((unsigned)(q1 & 255) << 8) |
         ((unsigned)(q2 & 255) << 16) | ((unsigned)(q3 & 255) << 24);
}

// ---------------- kernel 1: bucket rows by cluster (16 blocks, fast) ----------------
__global__ __launch_bounds__(256) void group_rows_kernel(
    const int* __restrict__ y, int* __restrict__ cnt, int* __restrict__ lists) {
  int r = blockIdx.x * 256 + threadIdx.x;
  if (r >= NROWS) return;
  int yy = y[r];
  int k = (yy < 2000) ? 0 : ((yy < 10000) ? 1 : 2);
  int pos = atomicAdd(&cnt[k], 1);
  lists[k * NROWS + pos] = r;
}

// ---------------- kernel 2: packW (banded, reg-prefetch) + packA + cll ----------------
// Wb8 16B-unit index (kt*VOCABN + col)*4 + (lg ^ ((col>>1)&3)) holds
// q(W[kt*64 + lg*16 + j][col]), j=0..15.  Band = 256 cols, 2 sub-iterations;
// BOTH sub-iterations' loads issued up front (T14: one latency exposure).
// Ab8 entry e = (g*8 + kstep)*64 + lane (16B) holds q(x[row=g*16+(lane&15)],
// k = kstep*64 + (lane>>4)*16 + j), j=0..15.
#define PACKW_BLOCKS 1568   // 8 kt x 196 bands of 256 cols
#define PACKA_BLOCKS 560    // (ASLOTS/16)*8*64/256
#define CLL_BLOCKS   1024   // NROWS/4
__global__ __launch_bounds__(256) void pack_all_kernel(
    const float* __restrict__ W, const float* __restrict__ x,
    const int* __restrict__ y, const float* __restrict__ cw,
    const float* __restrict__ cb,
    const int* __restrict__ cnt, const int* __restrict__ lists,
    char* __restrict__ Wb8, char* __restrict__ Ab8, float* __restrict__ cll) {
  __shared__ float lds[64][132];
  const int b = blockIdx.x;
  const int tid = threadIdx.x;
  if (b < PACKW_BLOCKS) {
    const int kt = b & 7;
    const int band0 = (b >> 3) * 256;
    const int c4 = (tid & 31) * 4;
    const int rbase = tid >> 5;
    // issue all 16 loads (both sub-iterations) up front
    float4 reg[2][8];
#pragma unroll
    for (int it = 0; it < 2; ++it) {
      int col0 = band0 + it * 128;
#pragma unroll
      for (int rr = 0; rr < 8; ++rr) {
        int r = rr * 8 + rbase;
        float4 v = (float4){0.f, 0.f, 0.f, 0.f};
        if (col0 + c4 < VOCABN)
          v = *reinterpret_cast<const float4*>(
              W + (size_t)(kt * 64 + r) * VOCABN + col0 + c4);
        reg[it][rr] = v;
      }
    }
#pragma unroll
    for (int it = 0; it < 2; ++it) {
      const int col0 = band0 + it * 128;
      if (col0 >= VOCABN) break;
#pragma unroll
      for (int rr = 0; rr < 8; ++rr)
        *reinterpret_cast<float4*>(&lds[rr * 8 + rbase][c4]) = reg[it][rr];
      __syncthreads();
#pragma unroll
      for (int t = 0; t < 2; ++t) {
        int o = tid + t * 256;
        int cc = o >> 2, lg = o & 3;
        int col = col0 + cc;
        if (col < VOCABN) {
          u32x4 d;
#pragma unroll
          for (int w = 0; w < 4; ++w)
            d[w] = q4(lds[lg * 16 + w * 4 + 0][cc], lds[lg * 16 + w * 4 + 1][cc],
                      lds[lg * 16 + w * 4 + 2][cc], lds[lg * 16 + w * 4 + 3][cc], WQS);
          int slot = lg ^ ((col >> 1) & 3);
          *reinterpret_cast<u32x4*>(
              Wb8 + ((size_t)(kt * VOCABN + col) * 4 + slot) * 16) = d;
        }
      }
      __syncthreads();   // LDS reuse fence before next sub-iteration
    }
    return;
  }
  if (b < PACKW_BLOCKS + PACKA_BLOCKS) {
    // ---- pack A ----
    int e = (b - PACKW_BLOCKS) * 256 + tid;
    int lane = e & 63;
    int kstep = (e >> 6) & 7;
    int g = e >> 9;
    int gslot = g * 16 + (lane & 15);
    int c0 = cnt[0], c1 = cnt[1], c2 = cnt[2];
    int p0 = (c0 + 127) & ~127, p1 = (c1 + 127) & ~127, p2 = (c2 + 127) & ~127;
    int k, slot, count;
    if (gslot < p0)                { k = 0; slot = gslot;           count = c0; }
    else if (gslot < p0 + p1)      { k = 1; slot = gslot - p0;      count = c1; }
    else if (gslot < p0 + p1 + p2) { k = 2; slot = gslot - p0 - p1; count = c2; }
    else return;
    int r = (count > 0) ? lists[k * NROWS + min(slot, count - 1)] : 0;
    const float* xr = x + (size_t)((r >> 10) * 1025 + (r & 1023)) * HIDN
                        + kstep * 64 + ((lane >> 4) & 3) * 16;
    float4 a = *reinterpret_cast<const float4*>(xr);
    float4 bb = *reinterpret_cast<const float4*>(xr + 4);
    float4 c = *reinterpret_cast<const float4*>(xr + 8);
    float4 dd = *reinterpret_cast<const float4*>(xr + 12);
    u32x4 d;
    d.x = q4(a.x, a.y, a.z, a.w, XQS);
    d.y = q4(bb.x, bb.y, bb.z, bb.w, XQS);
    d.z = q4(c.x, c.y, c.z, c.w, XQS);
    d.w = q4(dd.x, dd.y, dd.z, dd.w, XQS);
    *reinterpret_cast<u32x4*>(Ab8 + (size_t)e * 16) = d;
    return;
  }
  // ---- cluster-head log-softmax (independent of grouping) ----
  int wv = tid >> 6, lane = tid & 63;
  int row = (b - PACKW_BLOCKS - PACKA_BLOCKS) * 4 + wv;
  if (row >= NROWS) return;
  const float* xr = x + (size_t)((row >> 10) * 1025 + (row & 1023)) * HIDN;
  float4 v0 = *reinterpret_cast<const float4*>(xr + lane * 8);
  float4 v1 = *reinterpret_cast<const float4*>(xr + lane * 8 + 4);
  float xs[8] = {v0.x, v0.y, v0.z, v0.w, v1.x, v1.y, v1.z, v1.w};
  float a0 = 0.f, a1 = 0.f, a2 = 0.f;
#pragma unroll
  for (int u = 0; u < 8; ++u) {
    int h = lane * 8 + u;
    a0 = fmaf(xs[u], cw[h * 3 + 0], a0);
    a1 = fmaf(xs[u], cw[h * 3 + 1], a1);
    a2 = fmaf(xs[u], cw[h * 3 + 2], a2);
  }
#pragma unroll
  for (int off = 32; off; off >>= 1) {
    a0 += __shfl_xor(a0, off, 64);
    a1 += __shfl_xor(a1, off, 64);
    a2 += __shfl_xor(a2, off, 64);
  }
  if (lane == 0) {
    a0 += cb[0]; a1 += cb[1]; a2 += cb[2];
    float m3 = fmaxf(a0, fmaxf(a1, a2));
    float lse = m3 + __logf(__expf(a0 - m3) + __expf(a1 - m3) + __expf(a2 - m3));
    int yy = y[row];
    float sel = (yy < 2000) ? a0 : ((yy < 10000) ? a1 : a2);
    cll[row] = sel - lse;
  }
}

// ---------------- main GEMM (int8 MFMA K=64) + exp2-sum ----------------
// r14/r12 frozen structure; additions this round: (a) s_setprio(1/0) around
// each MFMA cluster (T5 -- blocks at different phases give the CU scheduler
// something to arbitrate), (b) exp2-folded epilogue (one v_mul less per
// logit; ztgt stores z2*ln2 = natural z, predicated on the rare target hit).
#define GRID_TOTAL 12544   // 392 groups x 32 m-blocks
__global__ __launch_bounds__(256, 4) void gemm_lse_i8(
    const char* __restrict__ Ab8, const char* __restrict__ Wb8,
    const float* __restrict__ lb, const int* __restrict__ cnt,
    const int* __restrict__ lists, const int* __restrict__ y,
    float* __restrict__ ps, float* __restrict__ ztgt) {
  const int hw = (int)blockIdx.x;
  const int xcd = hw & 7;
  const int idx = hw >> 3;               // 0..1567
  const int g = xcd + ((idx >> 5) << 3); // group 0..391 (bijective)
  const int mb = idx & 31;
  int k, ns;
  if (g < 16)      { k = 0; ns = g; }
  else if (g < 79) { k = 1; ns = g - 16; }
  else             { k = 2; ns = g - 79; }
  const int count = cnt[k];
  const int slot0 = mb * 128;
  if (slot0 >= count) return;
  const int LOk = (k == 0) ? 0 : ((k == 1) ? 2000 : 10000);
  const int HIk = (k == 0) ? 2000 : ((k == 1) ? 10000 : VOCABN);
  const int NSOFF = (k == 0) ? 0 : ((k == 1) ? 16 : 79);
  const int col0 = LOk + ns * 128;
  const int p0 = (cnt[0] + 127) & ~127, p1 = (cnt[1] + 127) & ~127;
  const int gbase = (k == 0) ? 0 : ((k == 1) ? p0 : p0 + p1);

  __shared__ __align__(16) char Bs[2][16384];
  __shared__ int rows_sh[128];
  __shared__ int tgt_sh[128];

  const int tid = threadIdx.x;
  const int lane = tid & 63;
  const int wr = tid >> 6;          // wave owns rows [wr*32, wr*32+32)
  const int l15 = lane & 15, lg = lane >> 4;
  const int swz = (l15 >> 1) & 3;   // col0 is a multiple of 16 -> local swz valid

  if (tid < 128) {
    int r = lists[k * NROWS + min(slot0 + tid, count - 1)];
    rows_sh[tid] = r;
    tgt_sh[tid] = y[r];
  }

  const char* Bbase = Wb8 + (size_t)col0 * 64;
  const char* Aw = Ab8 + (((size_t)(gbase + slot0) >> 4) + wr * 2) * 8192
                       + (size_t)lane * 16;

  auto stageB = [&](int p, int b) {
    int off = tid * 16;
#pragma unroll
    for (int h = 0; h < 2; ++h) {
      const char* src = Bbase + (size_t)(2 * p + h) * ((size_t)VOCABN * 64);
      gload_lds16(src + off, &Bs[b][h * 8192 + off]);
      gload_lds16(src + off + 4096, &Bs[b][h * 8192 + off + 4096]);
    }
  };

  i32x4 acc[2][8];
#pragma unroll
  for (int mi = 0; mi < 2; ++mi)
#pragma unroll
    for (int ni = 0; ni < 8; ++ni) acc[mi][ni] = (i32x4){0, 0, 0, 0};

  stageB(0, 0);
  __syncthreads();  // tile 0 + rows_sh ready

  int cur = 0;
  for (int p = 0; p < 4; ++p) {
    if (p < 3) stageB(p + 1, cur ^ 1);  // in flight across the whole compute
#pragma unroll
    for (int ks = 0; ks < 2; ++ks) {
      const int kstep = p * 2 + ks;
      i32x4 af[2];
#pragma unroll
      for (int mi = 0; mi < 2; ++mi)
        af[mi] = *reinterpret_cast<const i32x4*>(Aw + mi * 8192 + kstep * 1024);
      i32x4 bf[8];
#pragma unroll
      for (int ni = 0; ni < 8; ++ni)
        bf[ni] = *reinterpret_cast<const i32x4*>(
            &Bs[cur][ks * 8192 + ((ni * 16 + l15) * 4 + (lg ^ swz)) * 16]);
      __builtin_amdgcn_s_setprio(1);
#pragma unroll
      for (int mi = 0; mi < 2; ++mi)
#pragma unroll
        for (int ni = 0; ni < 8; ++ni)
          acc[mi][ni] = __builtin_amdgcn_mfma_i32_16x16x64_i8(
              af[mi], bf[ni], acc[mi][ni], 0, 0, 0);
      __builtin_amdgcn_s_setprio(0);
    }
    __syncthreads();  // drains stage vmcnt (post-compute) + buffer-reuse fence
    cur ^= 1;
  }

  // ---- epilogue: exp2-folded dequant+bias, target capture, sum ----
  const float DEQ2 = DEQ * L2E;
  float bias2[8]; int colx[8]; bool okc[8];
#pragma unroll
  for (int ni = 0; ni < 8; ++ni) {
    int col = col0 + ni * 16 + l15;
    colx[ni] = col;
    okc[ni] = (col < HIk);
    bias2[ni] = okc[ni] ? lb[col] * L2E : 0.f;
  }
#pragma unroll
  for (int mi = 0; mi < 2; ++mi) {
#pragma unroll
    for (int r = 0; r < 4; ++r) {
      int rowl = wr * 32 + mi * 16 + lg * 4 + r;
      int tgt = tgt_sh[rowl];
      float s = 0.f;
#pragma unroll
      for (int ni = 0; ni < 8; ++ni) {
        float z2 = fmaf((float)acc[mi][ni][r], DEQ2, bias2[ni]);
        if (colx[ni] == tgt) ztgt[rows_sh[rowl]] = z2 * LN2;
        s += okc[ni] ? exp2f(z2) : 0.f;
      }
#pragma unroll
      for (int off = 1; off < 16; off <<= 1)
        s += __shfl_xor(s, off, 64);
      if (l15 == 0) {
        int slot = slot0 + rowl;
        if (slot < count)
          ps[(size_t)(NSOFF + ns) * NROWS + slot] = s;
      }
    }
  }
}

// ---------------- combine v2: coalesced, latency-parallel ----------------
__global__ __launch_bounds__(256) void combine_v2_kernel(
    const int* __restrict__ cnt, const int* __restrict__ lists,
    const float* __restrict__ ps, const float* __restrict__ cll,
    const float* __restrict__ ztgt, float* __restrict__ out) {
  __shared__ float part[4][64];
  int b = blockIdx.x;            // 0..191
  int k = b >> 6;
  int slot0 = (b & 63) * 64;
  int count = cnt[k];
  if (slot0 >= count) return;
  int NCH = (k == 0) ? 16 : ((k == 1) ? 63 : 313);
  int NSOFF = (k == 0) ? 0 : ((k == 1) ? 16 : 79);
  int q = threadIdx.x >> 6, sl = threadIdx.x & 63;
  float s = 0.f;
  for (int ns = q; ns < NCH; ns += 4)
    s += ps[(size_t)(NSOFF + ns) * NROWS + slot0 + sl];
  part[q][sl] = s;
  __syncthreads();
  if (threadIdx.x < 64) {
    int slot = slot0 + threadIdx.x;
    if (slot < count) {
      float t = part[0][threadIdx.x] + part[1][threadIdx.x] +
                part[2][threadIdx.x] + part[3][threadIdx.x];
      int row = lists[k * NROWS + slot];
      out[row] = -(cll[row] + ztgt[row] - __logf(t));
    }
  }
}

// ---------------- fallback (round-2 proven path, low ws need) ----------------
__global__ __launch_bounds__(256, 2) void tail_mfma_fb(
    const float* __restrict__ x, const int* __restrict__ y,
    const float* __restrict__ W, const float* __restrict__ lb,
    const int* __restrict__ cnt, const int* __restrict__ lists,
    float* __restrict__ pm, float* __restrict__ ps, float* __restrict__ ztgt) {
  const int k = blockIdx.z;
  const int NSk = (k == 0) ? 2 : ((k == 1) ? 8 : 40);
  const int ns = blockIdx.y;
  if (ns >= NSk) return;
  const int count = cnt[k];
  const int base = blockIdx.x * MTILE;
  if (base >= count) return;
  const int LOk   = (k == 0) ? 0 : ((k == 1) ? 2000 : 10000);
  const int NFRAG = ((k == 0) ? 2000 : ((k == 1) ? 8000 : 40000)) >> 4;
  const int NSOFF = (k == 0) ? 0 : ((k == 1) ? 2 : 10);
  const int flo = ns * FPB;
  const int fhi = min(NFRAG, flo + FPB);
  const int tid = threadIdx.x;
  const int lane = tid & 63;
  const int wv = tid >> 6;
  const int l15 = lane & 15;
  const int lg = lane >> 4;

  __shared__ int rows_sh[MTILE];
  __shared__ int tgt_sh[MTILE];
  __shared__ float redm[4][MTILE];
  __shared__ float reds[4][MTILE];

  if (tid < MTILE) {
    int r = lists[k * NROWS + min(base + tid, count - 1)];
    rows_sh[tid] = r;
    tgt_sh[tid] = y[r];
  }
  __syncthreads();

  const float4* xq[4];
#pragma unroll
  for (int mf = 0; mf < 4; ++mf) {
    int r = rows_sh[mf * 16 + l15];
    xq[mf] = reinterpret_cast<const float4*>(
                 x + (size_t)((r >> 10) * 1025 + (r & 1023)) * HIDN) + lg * 2;
  }
  int tc[16];
#pragma unroll
  for (int mf = 0; mf < 4; ++mf)
#pragma unroll
    for (int r = 0; r < 4; ++r) tc[mf * 4 + r] = tgt_sh[mf * 16 + lg * 4 + r];

  float mM[16], sS[16];
#pragma unroll
  for (int i = 0; i < 16; ++i) { mM[i] = -INFINITY; sS[i] = 0.f; }
  const unsigned kg_off = (unsigned)(lg * 8) * VOCABN;

  for (int f0 = flo + wv; f0 < fhi; f0 += 16) {
    int fc[4];
    bool val[4];
    unsigned vb[4];
    float biasv[4];
#pragma unroll
    for (int c = 0; c < 4; ++c) {
      int f = f0 + 4 * c;
      val[c] = (f < fhi);
      if (!val[c]) f = fhi - 1;
      fc[c] = f;
      unsigned col = (unsigned)(LOk + f * 16 + l15);
      vb[c] = kg_off + col;
      biasv[c] = lb[col];
    }
    f32x4 acc[4][4];
#pragma unroll
    for (int c = 0; c < 4; ++c)
#pragma unroll
      for (int mf = 0; mf < 4; ++mf) acc[c][mf] = (f32x4){0.f, 0.f, 0.f, 0.f};

    for (int ks = 0; ks < 16; ++ks) {
      bf16x8 afr[4];
#pragma unroll
      for (int mf = 0; mf < 4; ++mf) {
        float4 x0 = xq[mf][ks * 8];
        float4 x1 = xq[mf][ks * 8 + 1];
        u32x4 d;
        d.x = pk2(x0.y, x0.x);
        d.y = pk2(x0.w, x0.z);
        d.z = pk2(x1.y, x1.x);
        d.w = pk2(x1.w, x1.z);
        afr[mf] = __builtin_bit_cast(bf16x8, d);
      }
      const float* Wk = W + (size_t)ks * 32 * VOCABN;
#pragma unroll
      for (int c = 0; c < 4; ++c) {
        float w0 = Wk[vb[c]];
        float w1 = (Wk + 1 * VOCABN)[vb[c]];
        float w2 = (Wk + 2 * VOCABN)[vb[c]];
        float w3 = (Wk + 3 * VOCABN)[vb[c]];
        float w4 = (Wk + 4 * VOCABN)[vb[c]];
        float w5 = (Wk + 5 * VOCABN)[vb[c]];
        float w6 = (Wk + 6 * VOCABN)[vb[c]];
        float w7 = (Wk + 7 * VOCABN)[vb[c]];
        u32x4 d;
        d.x = pk2(w1, w0);
        d.y = pk2(w3, w2);
        d.z = pk2(w5, w4);
        d.w = pk2(w7, w6);
        bf16x8 bfr = __builtin_bit_cast(bf16x8, d);
#pragma unroll
        for (int mf = 0; mf < 4; ++mf)
          acc[c][mf] = __builtin_amdgcn_mfma_f32_16x16x32_bf16(
              afr[mf], bfr, acc[c][mf], 0, 0, 0);
      }
    }
#pragma unroll
    for (int c = 0; c < 4; ++c) {
      if (!val[c]) continue;
      int col = LOk + fc[c] * 16 + l15;
#pragma unroll
      for (int mf = 0; mf < 4; ++mf)
#pragma unroll
        for (int r = 0; r < 4; ++r) {
          float z = acc[c][mf][r] + biasv[c];
          int i = mf * 4 + r;
          if (tc[i] == col) ztgt[rows_sh[mf * 16 + lg * 4 + r]] = z;
          float nm = fmaxf(mM[i], z);
          sS[i] = sS[i] * __expf(mM[i] - nm) + __expf(z - nm);
          mM[i] = nm;
        }
    }
  }
#pragma unroll
  for (int i = 0; i < 16; ++i) {
    float m = mM[i], s = sS[i];
#pragma unroll
    for (int off = 1; off < 16; off <<= 1) {
      float m2 = __shfl_xor(m, off, 64);
      float s2 = __shfl_xor(s, off, 64);
      float nm = fmaxf(m, m2);
      s = s * __expf(m - nm) + s2 * __expf(m2 - nm);
      m = nm;
    }
    mM[i] = m; sS[i] = s;
  }
  if (l15 == 0) {
#pragma unroll
    for (int mf = 0; mf < 4; ++mf)
#pragma unroll
      for (int r = 0; r < 4; ++r) {
        redm[wv][mf * 16 + lg * 4 + r] = mM[mf * 4 + r];
        reds[wv][mf * 16 + lg * 4 + r] = sS[mf * 4 + r];
      }
  }
  __syncthreads();
  if (tid < MTILE) {
    float m = redm[0][tid], s = reds[0][tid];
#pragma unroll
    for (int w = 1; w < 4; ++w) {
      float m2 = redm[w][tid], s2 = reds[w][tid];
      float nm = fmaxf(m, m2);
      s = s * __expf(m - nm) + s2 * __expf(m2 - nm);
      m = nm;
    }
    pm[(NSOFF + ns) * NROWS + base + tid] = m;
    ps[(NSOFF + ns) * NROWS + base + tid] = s;
  }
}

__global__ __launch_bounds__(256) void combine_fb_kernel(
    const int* __restrict__ cnt, const int* __restrict__ lists,
    const float* __restrict__ pm, const float* __restrict__ ps,
    const float* __restrict__ cll, const float* __restrict__ ztgt,
    float* __restrict__ out) {
  int t = blockIdx.x * 256 + threadIdx.x;
  if (t >= 3 * NROWS) return;
  int k = t / NROWS, slot = t % NROWS;
  if (slot >= cnt[k]) return;
  int row = lists[k * NROWS + slot];
  int NSk = (k == 0) ? 2 : ((k == 1) ? 8 : 40);
  int NSO = (k == 0) ? 0 : ((k == 1) ? 2 : 10);
  float m = -INFINITY, s = 0.f;
  for (int ns = 0; ns < NSk; ++ns) {
    float m2 = pm[(NSO + ns) * NROWS + slot];
    float s2 = ps[(NSO + ns) * NROWS + slot];
    float nm = fmaxf(m, m2);
    float e1 = (m == -INFINITY) ? 0.f : __expf(m - nm);
    float e2 = (m2 == -INFINITY) ? 0.f : __expf(m2 - nm);
    s = s * e1 + s2 * e2;
    m = nm;
  }
  out[row] = -(cll[row] + ztgt[row] - (m + __logf(s)));
}

// fallback cll (only used on fallback path)
__global__ __launch_bounds__(256) void cll_kernel(
    const float* __restrict__ x, const int* __restrict__ y,
    const float* __restrict__ cw, const float* __restrict__ cb,
    float* __restrict__ cll) {
  int wv = threadIdx.x >> 6, lane = threadIdx.x & 63;
  int row = blockIdx.x * 4 + wv;
  if (row >= NROWS) return;
  const float* xr = x + (size_t)((row >> 10) * 1025 + (row & 1023)) * HIDN;
  float4 v0 = *reinterpret_cast<const float4*>(xr + lane * 8);
  float4 v1 = *reinterpret_cast<const float4*>(xr + lane * 8 + 4);
  float xs[8] = {v0.x, v0.y, v0.z, v0.w, v1.x, v1.y, v1.z, v1.w};
  float a0 = 0.f, a1 = 0.f, a2 = 0.f;
#pragma unroll
  for (int u = 0; u < 8; ++u) {
    int h = lane * 8 + u;
    a0 = fmaf(xs[u], cw[h * 3 + 0], a0);
    a1 = fmaf(xs[u], cw[h * 3 + 1], a1);
    a2 = fmaf(xs[u], cw[h * 3 + 2], a2);
  }
#pragma unroll
  for (int off = 32; off; off >>= 1) {
    a0 += __shfl_xor(a0, off, 64);
    a1 += __shfl_xor(a1, off, 64);
    a2 += __shfl_xor(a2, off, 64);
  }
  if (lane == 0) {
    a0 += cb[0]; a1 += cb[1]; a2 += cb[2];
    float m3 = fmaxf(a0, fmaxf(a1, a2));
    float lse = m3 + __logf(__expf(a0 - m3) + __expf(a1 - m3) + __expf(a2 - m3));
    int yy = y[row];
    float sel = (yy < 2000) ? a0 : ((yy < 10000) ? a1 : a2);
    cll[row] = sel - lse;
  }
}

extern "C" void kernel_launch(void* const* d_in, const int* in_sizes, int n_in,
                              void* d_out, int out_size, void* d_ws, size_t ws_size,
                              hipStream_t stream) {
  (void)in_sizes; (void)n_in; (void)out_size;
  const float* x  = (const float*)d_in[0];
  const int*   y  = (const int*)d_in[1];
  const float* cw = (const float*)d_in[2];
  const float* cb = (const float*)d_in[3];
  const float* W  = (const float*)d_in[4];
  const float* lb = (const float*)d_in[5];
  float* out = (float*)d_out;

  char* ws = (char*)d_ws;
  int*   cnt   = (int*)(ws + 0);           // 1024
  int*   lists = (int*)(ws + 1024);        // 49152  -> 50176
  float* cll   = (float*)(ws + 50176);     // 16384  -> 66560
  float* ztgt  = (float*)(ws + 66560);     // 16384  -> 82944
  float* pm    = (float*)(ws + 82944);     // 6422528 -> 6505472 (fallback only)
  float* ps    = (float*)(ws + 6505472);   // 6422528 -> 12928000
  char*  Ab8   = ws + 12928000;            // ASLOTS*512 = 2293760 -> 15221760
  char*  Wb8   = ws + 15221760;            // 8*50000*64 = 25600000 -> 40821760
  const size_t WS_NEED = 40821760u;

  hipMemsetAsync(cnt, 0, 16, stream);
  group_rows_kernel<<<16, 256, 0, stream>>>(y, cnt, lists);
  if (ws_size >= WS_NEED) {
    pack_all_kernel<<<PACKW_BLOCKS + PACKA_BLOCKS + CLL_BLOCKS, 256, 0, stream>>>(
        W, x, y, cw, cb, cnt, lists, Wb8, Ab8, cll);
    gemm_lse_i8<<<GRID_TOTAL, 256, 0, stream>>>(Ab8, Wb8, lb, cnt, lists, y, ps, ztgt);
    combine_v2_kernel<<<192, 256, 0, stream>>>(cnt, lists, ps, cll, ztgt, out);
  } else {
    cll_kernel<<<NROWS / 4, 256, 0, stream>>>(x, y, cw, cb, cll);
    dim3 tg(NROWS / MTILE, MAXNS, 3);
    tail_mfma_fb<<<tg, 256, 0, stream>>>(x, y, W, lb, cnt, lists, pm, ps, ztgt);
    combine_fb_kernel<<<(3 * NROWS + 255) / 256, 256, 0, stream>>>(
        cnt, lists, pm, ps, cll, ztgt, out);
  }
}

// Round 18
// 183.502 us; speedup vs baseline: 1.0842x; 1.0842x over previous
//
#include <hip/hip_runtime.h>
#include <math.h>

#define VOCABN 50000
#define HIDN 512
#define NROWS 4096
#define MTILE 64
#define FPB 64
#define MAXNS 40
#define ASLOTS 4480   // padded grouped-slot space (>= 4096 + 3*127), multiple of 16

typedef __attribute__((ext_vector_type(8))) short bf16x8;
typedef __attribute__((ext_vector_type(4))) float f32x4;
typedef __attribute__((ext_vector_type(4))) unsigned u32x4;
typedef __attribute__((ext_vector_type(4))) int i32x4;

#define XQS 15.875f          // 127/8  (x scale)
#define WQS 3175.0f          // 127/0.04 (w scale)
#define DEQ ((8.0f / 127.0f) * (0.04f / 127.0f))

// pack two fp32 into 2 bf16 (truncate): low16 = bf16(lo), high16 = bf16(hi)
__device__ __forceinline__ unsigned pk2(float hi, float lo) {
  return __builtin_amdgcn_perm(__builtin_bit_cast(unsigned, hi),
                               __builtin_bit_cast(unsigned, lo),
                               0x07060302u);
}

__device__ __forceinline__ void gload_lds16(const void* g, void* l) {
  __builtin_amdgcn_global_load_lds(
      (const __attribute__((address_space(1))) void*)g,
      (__attribute__((address_space(3))) void*)l, 16, 0, 0);
}

__device__ __forceinline__ unsigned q4(float a, float b, float c, float d, float s) {
  int q0 = max(-127, min(127, __float2int_rn(a * s)));
  int q1 = max(-127, min(127, __float2int_rn(b * s)));
  int q2 = max(-127, min(127, __float2int_rn(c * s)));
  int q3 = max(-127, min(127, __float2int_rn(d * s)));
  return (unsigned)(q0 & 255) | ((unsigned)(q1 & 255) << 8) |
         ((unsigned)(q2 & 255) << 16) | ((unsigned)(q3 & 255) << 24);
}

// ---------------- kernel 1: bucket rows by cluster (16 blocks, fast) ----------------
__global__ __launch_bounds__(256) void group_rows_kernel(
    const int* __restrict__ y, int* __restrict__ cnt, int* __restrict__ lists) {
  int r = blockIdx.x * 256 + threadIdx.x;
  if (r >= NROWS) return;
  int yy = y[r];
  int k = (yy < 2000) ? 0 : ((yy < 10000) ? 1 : 2);
  int pos = atomicAdd(&cnt[k], 1);
  lists[k * NROWS + pos] = r;
}

// ---------------- kernel 2: packW (banded, reg-prefetch) + packA + cll ----------------
// Wb8 16B-unit index (kt*VOCABN + col)*4 + (lg ^ ((col>>1)&3)) holds
// q(W[kt*64 + lg*16 + j][col]), j=0..15.  Band = 256 cols, 2 sub-iterations;
// BOTH sub-iterations' loads issued up front (T14: one latency exposure).
// Ab8 entry e = (g*8 + kstep)*64 + lane (16B) holds q(x[row=g*16+(lane&15)],
// k = kstep*64 + (lane>>4)*16 + j), j=0..15.
#define PACKW_BLOCKS 1568   // 8 kt x 196 bands of 256 cols
#define PACKA_BLOCKS 560    // (ASLOTS/16)*8*64/256
#define CLL_BLOCKS   1024   // NROWS/4
__global__ __launch_bounds__(256) void pack_all_kernel(
    const float* __restrict__ W, const float* __restrict__ x,
    const int* __restrict__ y, const float* __restrict__ cw,
    const float* __restrict__ cb,
    const int* __restrict__ cnt, const int* __restrict__ lists,
    char* __restrict__ Wb8, char* __restrict__ Ab8, float* __restrict__ cll) {
  __shared__ float lds[64][132];
  const int b = blockIdx.x;
  const int tid = threadIdx.x;
  if (b < PACKW_BLOCKS) {
    const int kt = b & 7;
    const int band0 = (b >> 3) * 256;
    const int c4 = (tid & 31) * 4;
    const int rbase = tid >> 5;
    // issue all 16 loads (both sub-iterations) up front
    float4 reg[2][8];
#pragma unroll
    for (int it = 0; it < 2; ++it) {
      int col0 = band0 + it * 128;
#pragma unroll
      for (int rr = 0; rr < 8; ++rr) {
        int r = rr * 8 + rbase;
        float4 v = (float4){0.f, 0.f, 0.f, 0.f};
        if (col0 + c4 < VOCABN)
          v = *reinterpret_cast<const float4*>(
              W + (size_t)(kt * 64 + r) * VOCABN + col0 + c4);
        reg[it][rr] = v;
      }
    }
#pragma unroll
    for (int it = 0; it < 2; ++it) {
      const int col0 = band0 + it * 128;
      if (col0 >= VOCABN) break;
#pragma unroll
      for (int rr = 0; rr < 8; ++rr)
        *reinterpret_cast<float4*>(&lds[rr * 8 + rbase][c4]) = reg[it][rr];
      __syncthreads();
#pragma unroll
      for (int t = 0; t < 2; ++t) {
        int o = tid + t * 256;
        int cc = o >> 2, lg = o & 3;
        int col = col0 + cc;
        if (col < VOCABN) {
          u32x4 d;
#pragma unroll
          for (int w = 0; w < 4; ++w)
            d[w] = q4(lds[lg * 16 + w * 4 + 0][cc], lds[lg * 16 + w * 4 + 1][cc],
                      lds[lg * 16 + w * 4 + 2][cc], lds[lg * 16 + w * 4 + 3][cc], WQS);
          int slot = lg ^ ((col >> 1) & 3);
          *reinterpret_cast<u32x4*>(
              Wb8 + ((size_t)(kt * VOCABN + col) * 4 + slot) * 16) = d;
        }
      }
      __syncthreads();   // LDS reuse fence before next sub-iteration
    }
    return;
  }
  if (b < PACKW_BLOCKS + PACKA_BLOCKS) {
    // ---- pack A ----
    int e = (b - PACKW_BLOCKS) * 256 + tid;
    int lane = e & 63;
    int kstep = (e >> 6) & 7;
    int g = e >> 9;
    int gslot = g * 16 + (lane & 15);
    int c0 = cnt[0], c1 = cnt[1], c2 = cnt[2];
    int p0 = (c0 + 127) & ~127, p1 = (c1 + 127) & ~127, p2 = (c2 + 127) & ~127;
    int k, slot, count;
    if (gslot < p0)                { k = 0; slot = gslot;           count = c0; }
    else if (gslot < p0 + p1)      { k = 1; slot = gslot - p0;      count = c1; }
    else if (gslot < p0 + p1 + p2) { k = 2; slot = gslot - p0 - p1; count = c2; }
    else return;
    int r = (count > 0) ? lists[k * NROWS + min(slot, count - 1)] : 0;
    const float* xr = x + (size_t)((r >> 10) * 1025 + (r & 1023)) * HIDN
                        + kstep * 64 + ((lane >> 4) & 3) * 16;
    float4 a = *reinterpret_cast<const float4*>(xr);
    float4 bb = *reinterpret_cast<const float4*>(xr + 4);
    float4 c = *reinterpret_cast<const float4*>(xr + 8);
    float4 dd = *reinterpret_cast<const float4*>(xr + 12);
    u32x4 d;
    d.x = q4(a.x, a.y, a.z, a.w, XQS);
    d.y = q4(bb.x, bb.y, bb.z, bb.w, XQS);
    d.z = q4(c.x, c.y, c.z, c.w, XQS);
    d.w = q4(dd.x, dd.y, dd.z, dd.w, XQS);
    *reinterpret_cast<u32x4*>(Ab8 + (size_t)e * 16) = d;
    return;
  }
  // ---- cluster-head log-softmax (independent of grouping) ----
  int wv = tid >> 6, lane = tid & 63;
  int row = (b - PACKW_BLOCKS - PACKA_BLOCKS) * 4 + wv;
  if (row >= NROWS) return;
  const float* xr = x + (size_t)((row >> 10) * 1025 + (row & 1023)) * HIDN;
  float4 v0 = *reinterpret_cast<const float4*>(xr + lane * 8);
  float4 v1 = *reinterpret_cast<const float4*>(xr + lane * 8 + 4);
  float xs[8] = {v0.x, v0.y, v0.z, v0.w, v1.x, v1.y, v1.z, v1.w};
  float a0 = 0.f, a1 = 0.f, a2 = 0.f;
#pragma unroll
  for (int u = 0; u < 8; ++u) {
    int h = lane * 8 + u;
    a0 = fmaf(xs[u], cw[h * 3 + 0], a0);
    a1 = fmaf(xs[u], cw[h * 3 + 1], a1);
    a2 = fmaf(xs[u], cw[h * 3 + 2], a2);
  }
#pragma unroll
  for (int off = 32; off; off >>= 1) {
    a0 += __shfl_xor(a0, off, 64);
    a1 += __shfl_xor(a1, off, 64);
    a2 += __shfl_xor(a2, off, 64);
  }
  if (lane == 0) {
    a0 += cb[0]; a1 += cb[1]; a2 += cb[2];
    float m3 = fmaxf(a0, fmaxf(a1, a2));
    float lse = m3 + __logf(__expf(a0 - m3) + __expf(a1 - m3) + __expf(a2 - m3));
    int yy = y[row];
    float sel = (yy < 2000) ? a0 : ((yy < 10000) ? a1 : a2);
    cll[row] = sel - lse;
  }
}

// ---------------- main GEMM (int8 MFMA K=64) + exp-sum ---- r16/r14/r12 exact ----------------
// 4 phases of K=128 (2 ksteps staged/phase), B-only LDS dbuf (2x16KB),
// A via coalesced reg loads, ONE __syncthreads per phase. Balanced
// group-interleave XCD mapping: 392 ns-groups = 8 x 49; group g -> xcd g%8.
// PROVEN 103us / MfmaUtil 30. Eight restructures/micro-opts regressed -- FROZEN.
#define GRID_TOTAL 12544   // 392 groups x 32 m-blocks
__global__ __launch_bounds__(256, 4) void gemm_lse_i8(
    const char* __restrict__ Ab8, const char* __restrict__ Wb8,
    const float* __restrict__ lb, const int* __restrict__ cnt,
    const int* __restrict__ lists, const int* __restrict__ y,
    float* __restrict__ ps, float* __restrict__ ztgt) {
  const int hw = (int)blockIdx.x;
  const int xcd = hw & 7;
  const int idx = hw >> 3;               // 0..1567
  const int g = xcd + ((idx >> 5) << 3); // group 0..391 (bijective)
  const int mb = idx & 31;
  int k, ns;
  if (g < 16)      { k = 0; ns = g; }
  else if (g < 79) { k = 1; ns = g - 16; }
  else             { k = 2; ns = g - 79; }
  const int count = cnt[k];
  const int slot0 = mb * 128;
  if (slot0 >= count) return;
  const int LOk = (k == 0) ? 0 : ((k == 1) ? 2000 : 10000);
  const int HIk = (k == 0) ? 2000 : ((k == 1) ? 10000 : VOCABN);
  const int NSOFF = (k == 0) ? 0 : ((k == 1) ? 16 : 79);
  const int col0 = LOk + ns * 128;
  const int p0 = (cnt[0] + 127) & ~127, p1 = (cnt[1] + 127) & ~127;
  const int gbase = (k == 0) ? 0 : ((k == 1) ? p0 : p0 + p1);

  __shared__ __align__(16) char Bs[2][16384];
  __shared__ int rows_sh[128];
  __shared__ int tgt_sh[128];

  const int tid = threadIdx.x;
  const int lane = tid & 63;
  const int wr = tid >> 6;          // wave owns rows [wr*32, wr*32+32)
  const int l15 = lane & 15, lg = lane >> 4;
  const int swz = (l15 >> 1) & 3;   // col0 is a multiple of 16 -> local swz valid

  if (tid < 128) {
    int r = lists[k * NROWS + min(slot0 + tid, count - 1)];
    rows_sh[tid] = r;
    tgt_sh[tid] = y[r];
  }

  const char* Bbase = Wb8 + (size_t)col0 * 64;
  const char* Aw = Ab8 + (((size_t)(gbase + slot0) >> 4) + wr * 2) * 8192
                       + (size_t)lane * 16;

  auto stageB = [&](int p, int b) {
    int off = tid * 16;
#pragma unroll
    for (int h = 0; h < 2; ++h) {
      const char* src = Bbase + (size_t)(2 * p + h) * ((size_t)VOCABN * 64);
      gload_lds16(src + off, &Bs[b][h * 8192 + off]);
      gload_lds16(src + off + 4096, &Bs[b][h * 8192 + off + 4096]);
    }
  };

  i32x4 acc[2][8];
#pragma unroll
  for (int mi = 0; mi < 2; ++mi)
#pragma unroll
    for (int ni = 0; ni < 8; ++ni) acc[mi][ni] = (i32x4){0, 0, 0, 0};

  stageB(0, 0);
  __syncthreads();  // tile 0 + rows_sh ready

  int cur = 0;
  for (int p = 0; p < 4; ++p) {
    if (p < 3) stageB(p + 1, cur ^ 1);  // in flight across the whole compute
#pragma unroll
    for (int ks = 0; ks < 2; ++ks) {
      const int kstep = p * 2 + ks;
      i32x4 af[2];
#pragma unroll
      for (int mi = 0; mi < 2; ++mi)
        af[mi] = *reinterpret_cast<const i32x4*>(Aw + mi * 8192 + kstep * 1024);
      i32x4 bf[8];
#pragma unroll
      for (int ni = 0; ni < 8; ++ni)
        bf[ni] = *reinterpret_cast<const i32x4*>(
            &Bs[cur][ks * 8192 + ((ni * 16 + l15) * 4 + (lg ^ swz)) * 16]);
#pragma unroll
      for (int mi = 0; mi < 2; ++mi)
#pragma unroll
        for (int ni = 0; ni < 8; ++ni)
          acc[mi][ni] = __builtin_amdgcn_mfma_i32_16x16x64_i8(
              af[mi], bf[ni], acc[mi][ni], 0, 0, 0);
    }
    __syncthreads();  // drains stage vmcnt (post-compute) + buffer-reuse fence
    cur ^= 1;
  }

  // ---- epilogue: dequant, bias, boundary mask, target capture, exp-sum ----
  float biasv[8]; int colx[8]; bool okc[8];
#pragma unroll
  for (int ni = 0; ni < 8; ++ni) {
    int col = col0 + ni * 16 + l15;
    colx[ni] = col;
    okc[ni] = (col < HIk);
    biasv[ni] = okc[ni] ? lb[col] : 0.f;
  }
#pragma unroll
  for (int mi = 0; mi < 2; ++mi) {
#pragma unroll
    for (int r = 0; r < 4; ++r) {
      int rowl = wr * 32 + mi * 16 + lg * 4 + r;
      int tgt = tgt_sh[rowl];
      float s = 0.f;
#pragma unroll
      for (int ni = 0; ni < 8; ++ni) {
        float z = (float)acc[mi][ni][r] * DEQ + biasv[ni];
        if (colx[ni] == tgt) ztgt[rows_sh[rowl]] = z;
        s += okc[ni] ? __expf(z) : 0.f;
      }
#pragma unroll
      for (int off = 1; off < 16; off <<= 1)
        s += __shfl_xor(s, off, 64);
      if (l15 == 0) {
        int slot = slot0 + rowl;
        if (slot < count)
          ps[(size_t)(NSOFF + ns) * NROWS + slot] = s;
      }
    }
  }
}

// ---------------- combine v2: coalesced, latency-parallel ----------------
__global__ __launch_bounds__(256) void combine_v2_kernel(
    const int* __restrict__ cnt, const int* __restrict__ lists,
    const float* __restrict__ ps, const float* __restrict__ cll,
    const float* __restrict__ ztgt, float* __restrict__ out) {
  __shared__ float part[4][64];
  int b = blockIdx.x;            // 0..191
  int k = b >> 6;
  int slot0 = (b & 63) * 64;
  int count = cnt[k];
  if (slot0 >= count) return;
  int NCH = (k == 0) ? 16 : ((k == 1) ? 63 : 313);
  int NSOFF = (k == 0) ? 0 : ((k == 1) ? 16 : 79);
  int q = threadIdx.x >> 6, sl = threadIdx.x & 63;
  float s = 0.f;
  for (int ns = q; ns < NCH; ns += 4)
    s += ps[(size_t)(NSOFF + ns) * NROWS + slot0 + sl];
  part[q][sl] = s;
  __syncthreads();
  if (threadIdx.x < 64) {
    int slot = slot0 + threadIdx.x;
    if (slot < count) {
      float t = part[0][threadIdx.x] + part[1][threadIdx.x] +
                part[2][threadIdx.x] + part[3][threadIdx.x];
      int row = lists[k * NROWS + slot];
      out[row] = -(cll[row] + ztgt[row] - __logf(t));
    }
  }
}

// ---------------- fallback (round-2 proven path, low ws need) ----------------
__global__ __launch_bounds__(256, 2) void tail_mfma_fb(
    const float* __restrict__ x, const int* __restrict__ y,
    const float* __restrict__ W, const float* __restrict__ lb,
    const int* __restrict__ cnt, const int* __restrict__ lists,
    float* __restrict__ pm, float* __restrict__ ps, float* __restrict__ ztgt) {
  const int k = blockIdx.z;
  const int NSk = (k == 0) ? 2 : ((k == 1) ? 8 : 40);
  const int ns = blockIdx.y;
  if (ns >= NSk) return;
  const int count = cnt[k];
  const int base = blockIdx.x * MTILE;
  if (base >= count) return;
  const int LOk   = (k == 0) ? 0 : ((k == 1) ? 2000 : 10000);
  const int NFRAG = ((k == 0) ? 2000 : ((k == 1) ? 8000 : 40000)) >> 4;
  const int NSOFF = (k == 0) ? 0 : ((k == 1) ? 2 : 10);
  const int flo = ns * FPB;
  const int fhi = min(NFRAG, flo + FPB);
  const int tid = threadIdx.x;
  const int lane = tid & 63;
  const int wv = tid >> 6;
  const int l15 = lane & 15;
  const int lg = lane >> 4;

  __shared__ int rows_sh[MTILE];
  __shared__ int tgt_sh[MTILE];
  __shared__ float redm[4][MTILE];
  __shared__ float reds[4][MTILE];

  if (tid < MTILE) {
    int r = lists[k * NROWS + min(base + tid, count - 1)];
    rows_sh[tid] = r;
    tgt_sh[tid] = y[r];
  }
  __syncthreads();

  const float4* xq[4];
#pragma unroll
  for (int mf = 0; mf < 4; ++mf) {
    int r = rows_sh[mf * 16 + l15];
    xq[mf] = reinterpret_cast<const float4*>(
                 x + (size_t)((r >> 10) * 1025 + (r & 1023)) * HIDN) + lg * 2;
  }
  int tc[16];
#pragma unroll
  for (int mf = 0; mf < 4; ++mf)
#pragma unroll
    for (int r = 0; r < 4; ++r) tc[mf * 4 + r] = tgt_sh[mf * 16 + lg * 4 + r];

  float mM[16], sS[16];
#pragma unroll
  for (int i = 0; i < 16; ++i) { mM[i] = -INFINITY; sS[i] = 0.f; }
  const unsigned kg_off = (unsigned)(lg * 8) * VOCABN;

  for (int f0 = flo + wv; f0 < fhi; f0 += 16) {
    int fc[4];
    bool val[4];
    unsigned vb[4];
    float biasv[4];
#pragma unroll
    for (int c = 0; c < 4; ++c) {
      int f = f0 + 4 * c;
      val[c] = (f < fhi);
      if (!val[c]) f = fhi - 1;
      fc[c] = f;
      unsigned col = (unsigned)(LOk + f * 16 + l15);
      vb[c] = kg_off + col;
      biasv[c] = lb[col];
    }
    f32x4 acc[4][4];
#pragma unroll
    for (int c = 0; c < 4; ++c)
#pragma unroll
      for (int mf = 0; mf < 4; ++mf) acc[c][mf] = (f32x4){0.f, 0.f, 0.f, 0.f};

    for (int ks = 0; ks < 16; ++ks) {
      bf16x8 afr[4];
#pragma unroll
      for (int mf = 0; mf < 4; ++mf) {
        float4 x0 = xq[mf][ks * 8];
        float4 x1 = xq[mf][ks * 8 + 1];
        u32x4 d;
        d.x = pk2(x0.y, x0.x);
        d.y = pk2(x0.w, x0.z);
        d.z = pk2(x1.y, x1.x);
        d.w = pk2(x1.w, x1.z);
        afr[mf] = __builtin_bit_cast(bf16x8, d);
      }
      const float* Wk = W + (size_t)ks * 32 * VOCABN;
#pragma unroll
      for (int c = 0; c < 4; ++c) {
        float w0 = Wk[vb[c]];
        float w1 = (Wk + 1 * VOCABN)[vb[c]];
        float w2 = (Wk + 2 * VOCABN)[vb[c]];
        float w3 = (Wk + 3 * VOCABN)[vb[c]];
        float w4 = (Wk + 4 * VOCABN)[vb[c]];
        float w5 = (Wk + 5 * VOCABN)[vb[c]];
        float w6 = (Wk + 6 * VOCABN)[vb[c]];
        float w7 = (Wk + 7 * VOCABN)[vb[c]];
        u32x4 d;
        d.x = pk2(w1, w0);
        d.y = pk2(w3, w2);
        d.z = pk2(w5, w4);
        d.w = pk2(w7, w6);
        bf16x8 bfr = __builtin_bit_cast(bf16x8, d);
#pragma unroll
        for (int mf = 0; mf < 4; ++mf)
          acc[c][mf] = __builtin_amdgcn_mfma_f32_16x16x32_bf16(
              afr[mf], bfr, acc[c][mf], 0, 0, 0);
      }
    }
#pragma unroll
    for (int c = 0; c < 4; ++c) {
      if (!val[c]) continue;
      int col = LOk + fc[c] * 16 + l15;
#pragma unroll
      for (int mf = 0; mf < 4; ++mf)
#pragma unroll
        for (int r = 0; r < 4; ++r) {
          float z = acc[c][mf][r] + biasv[c];
          int i = mf * 4 + r;
          if (tc[i] == col) ztgt[rows_sh[mf * 16 + lg * 4 + r]] = z;
          float nm = fmaxf(mM[i], z);
          sS[i] = sS[i] * __expf(mM[i] - nm) + __expf(z - nm);
          mM[i] = nm;
        }
    }
  }
#pragma unroll
  for (int i = 0; i < 16; ++i) {
    float m = mM[i], s = sS[i];
#pragma unroll
    for (int off = 1; off < 16; off <<= 1) {
      float m2 = __shfl_xor(m, off, 64);
      float s2 = __shfl_xor(s, off, 64);
      float nm = fmaxf(m, m2);
      s = s * __expf(m - nm) + s2 * __expf(m2 - nm);
      m = nm;
    }
    mM[i] = m; sS[i] = s;
  }
  if (l15 == 0) {
#pragma unroll
    for (int mf = 0; mf < 4; ++mf)
#pragma unroll
      for (int r = 0; r < 4; ++r) {
        redm[wv][mf * 16 + lg * 4 + r] = mM[mf * 4 + r];
        reds[wv][mf * 16 + lg * 4 + r] = sS[mf * 4 + r];
      }
  }
  __syncthreads();
  if (tid < MTILE) {
    float m = redm[0][tid], s = reds[0][tid];
#pragma unroll
    for (int w = 1; w < 4; ++w) {
      float m2 = redm[w][tid], s2 = reds[w][tid];
      float nm = fmaxf(m, m2);
      s = s * __expf(m - nm) + s2 * __expf(m2 - nm);
      m = nm;
    }
    pm[(NSOFF + ns) * NROWS + base + tid] = m;
    ps[(NSOFF + ns) * NROWS + base + tid] = s;
  }
}

__global__ __launch_bounds__(256) void combine_fb_kernel(
    const int* __restrict__ cnt, const int* __restrict__ lists,
    const float* __restrict__ pm, const float* __restrict__ ps,
    const float* __restrict__ cll, const float* __restrict__ ztgt,
    float* __restrict__ out) {
  int t = blockIdx.x * 256 + threadIdx.x;
  if (t >= 3 * NROWS) return;
  int k = t / NROWS, slot = t % NROWS;
  if (slot >= cnt[k]) return;
  int row = lists[k * NROWS + slot];
  int NSk = (k == 0) ? 2 : ((k == 1) ? 8 : 40);
  int NSO = (k == 0) ? 0 : ((k == 1) ? 2 : 10);
  float m = -INFINITY, s = 0.f;
  for (int ns = 0; ns < NSk; ++ns) {
    float m2 = pm[(NSO + ns) * NROWS + slot];
    float s2 = ps[(NSO + ns) * NROWS + slot];
    float nm = fmaxf(m, m2);
    float e1 = (m == -INFINITY) ? 0.f : __expf(m - nm);
    float e2 = (m2 == -INFINITY) ? 0.f : __expf(m2 - nm);
    s = s * e1 + s2 * e2;
    m = nm;
  }
  out[row] = -(cll[row] + ztgt[row] - (m + __logf(s)));
}

// fallback cll (only used on fallback path)
__global__ __launch_bounds__(256) void cll_kernel(
    const float* __restrict__ x, const int* __restrict__ y,
    const float* __restrict__ cw, const float* __restrict__ cb,
    float* __restrict__ cll) {
  int wv = threadIdx.x >> 6, lane = threadIdx.x & 63;
  int row = blockIdx.x * 4 + wv;
  if (row >= NROWS) return;
  const float* xr = x + (size_t)((row >> 10) * 1025 + (row & 1023)) * HIDN;
  float4 v0 = *reinterpret_cast<const float4*>(xr + lane * 8);
  float4 v1 = *reinterpret_cast<const float4*>(xr + lane * 8 + 4);
  float xs[8] = {v0.x, v0.y, v0.z, v0.w, v1.x, v1.y, v1.z, v1.w};
  float a0 = 0.f, a1 = 0.f, a2 = 0.f;
#pragma unroll
  for (int u = 0; u < 8; ++u) {
    int h = lane * 8 + u;
    a0 = fmaf(xs[u], cw[h * 3 + 0], a0);
    a1 = fmaf(xs[u], cw[h * 3 + 1], a1);
    a2 = fmaf(xs[u], cw[h * 3 + 2], a2);
  }
#pragma unroll
  for (int off = 32; off; off >>= 1) {
    a0 += __shfl_xor(a0, off, 64);
    a1 += __shfl_xor(a1, off, 64);
    a2 += __shfl_xor(a2, off, 64);
  }
  if (lane == 0) {
    a0 += cb[0]; a1 += cb[1]; a2 += cb[2];
    float m3 = fmaxf(a0, fmaxf(a1, a2));
    float lse = m3 + __logf(__expf(a0 - m3) + __expf(a1 - m3) + __expf(a2 - m3));
    int yy = y[row];
    float sel = (yy < 2000) ? a0 : ((yy < 10000) ? a1 : a2);
    cll[row] = sel - lse;
  }
}

extern "C" void kernel_launch(void* const* d_in, const int* in_sizes, int n_in,
                              void* d_out, int out_size, void* d_ws, size_t ws_size,
                              hipStream_t stream) {
  (void)in_sizes; (void)n_in; (void)out_size;
  const float* x  = (const float*)d_in[0];
  const int*   y  = (const int*)d_in[1];
  const float* cw = (const float*)d_in[2];
  const float* cb = (const float*)d_in[3];
  const float* W  = (const float*)d_in[4];
  const float* lb = (const float*)d_in[5];
  float* out = (float*)d_out;

  char* ws = (char*)d_ws;
  int*   cnt   = (int*)(ws + 0);           // 1024
  int*   lists = (int*)(ws + 1024);        // 49152  -> 50176
  float* cll   = (float*)(ws + 50176);     // 16384  -> 66560
  float* ztgt  = (float*)(ws + 66560);     // 16384  -> 82944
  float* pm    = (float*)(ws + 82944);     // 6422528 -> 6505472 (fallback only)
  float* ps    = (float*)(ws + 6505472);   // 6422528 -> 12928000
  char*  Ab8   = ws + 12928000;            // ASLOTS*512 = 2293760 -> 15221760
  char*  Wb8   = ws + 15221760;            // 8*50000*64 = 25600000 -> 40821760
  const size_t WS_NEED = 40821760u;

  hipMemsetAsync(cnt, 0, 16, stream);
  group_rows_kernel<<<16, 256, 0, stream>>>(y, cnt, lists);
  if (ws_size >= WS_NEED) {
    pack_all_kernel<<<PACKW_BLOCKS + PACKA_BLOCKS + CLL_BLOCKS, 256, 0, stream>>>(
        W, x, y, cw, cb, cnt, lists, Wb8, Ab8, cll);
    gemm_lse_i8<<<GRID_TOTAL, 256, 0, stream>>>(Ab8, Wb8, lb, cnt, lists, y, ps, ztgt);
    combine_v2_kernel<<<192, 256, 0, stream>>>(cnt, lists, ps, cll, ztgt, out);
  } else {
    cll_kernel<<<NROWS / 4, 256, 0, stream>>>(x, y, cw, cb, cll);
    dim3 tg(NROWS / MTILE, MAXNS, 3);
    tail_mfma_fb<<<tg, 256, 0, stream>>>(x, y, W, lb, cnt, lists, pm, ps, ztgt);
    combine_fb_kernel<<<(3 * NROWS + 255) / 256, 256, 0, stream>>>(
        cnt, lists, pm, ps, cll, ztgt, out);
  }
}